// Round 2
// baseline (241.257 us; speedup 1.0000x reference)
//
#include <hip/hip_runtime.h>

// Problem shape (fixed by setup_inputs):
//   b=4, t_q=128, t_k=512, n_q=n_k=512, out_size=512
// ALL inputs/outputs are float32 (per reference). Output buffer layout:
//   [out (4*128*512 fp32), probs (4*128*512 fp32)]

#define BB    4
#define TQ    128
#define TK    512
#define NN    512
#define OUTSZ 512
#define CATSZ 1024

#if __has_builtin(__builtin_amdgcn_exp2f)
#define EXP2F(x) __builtin_amdgcn_exp2f(x)
#else
#define EXP2F(x) exp2f(x)
#endif
#if __has_builtin(__builtin_amdgcn_rcpf)
#define RCPF(x) __builtin_amdgcn_rcpf(x)
#else
#define RCPF(x) (1.0f / (x))
#endif

// tanh(x) = 1 - 2/(exp(2x)+1); exp(2x) = exp2(x * 2*log2(e)).
// Saturates correctly: x->+inf => exp2->inf => rcp->0 => 1; x->-inf => exp2->0 => -1.
__device__ __forceinline__ float fast_tanh(float x) {
  float e = EXP2F(x * 2.8853900817779268f);
  return fmaf(-2.0f, RCPF(e + 1.0f), 1.0f);
}
__device__ __forceinline__ float waveRedSum(float s) {
  #pragma unroll
  for (int m = 32; m >= 1; m >>= 1) s += __shfl_xor(s, m, 64);
  return s;
}
__device__ __forceinline__ float waveRedMax(float s) {
  #pragma unroll
  for (int m = 32; m >= 1; m >>= 1) s = fmaxf(s, __shfl_xor(s, m, 64));
  return s;
}

__global__ __launch_bounds__(512, 4)
void attn_fused_kernel(const float* __restrict__ query,   // [4,128,512]
                       const float* __restrict__ keys,    // [4,512,512]
                       const float* __restrict__ values,  // [4,512,512]
                       const float* __restrict__ W_q,     // [512,512]  (n,d)
                       const float* __restrict__ b_q,     // [512]
                       const float* __restrict__ w_att,   // [512]
                       const float* __restrict__ b_att,   // [1]
                       const float* __restrict__ W_out,   // [512,1024] (o,c)
                       const float* __restrict__ b_out,   // [512]
                       float* __restrict__ out,           // [4,128,512]
                       float* __restrict__ probs)         // [4,128,512]
{
  __shared__ float cat[CATSZ];   // [0:512) query row, [512:1024) context
  __shared__ float attq[NN];     // att_query row
  __shared__ float sc[TK];       // scores -> probs
  __shared__ float red[8];       // cross-wave reduce scratch

  const int bq   = blockIdx.x;        // 0..511 => (b, q)
  const int b    = bq >> 7;
  const int tid  = threadIdx.x;       // 0..511
  const int wave = tid >> 6;          // 0..7
  const int lane = tid & 63;

  // ---- stage query row into LDS (cat[0:512)) ----
  const float* qrow_g = query + (size_t)bq * NN;
  cat[tid] = qrow_g[tid];
  __syncthreads();

  // Per-lane register caches: elements n/d = lane*8 + j
  float qr[8], wr[8];
  {
    const float4* wv = (const float4*)(w_att + lane * 8);
    float4 w0 = wv[0], w1 = wv[1];
    wr[0]=w0.x; wr[1]=w0.y; wr[2]=w0.z; wr[3]=w0.w;
    wr[4]=w1.x; wr[5]=w1.y; wr[6]=w1.z; wr[7]=w1.w;
    #pragma unroll
    for (int j = 0; j < 8; ++j) qr[j] = cat[lane * 8 + j];
  }

  // ---- step 1: att_q[n] = b_q[n] + sum_d query[d] * W_q[n,d] ----
  #pragma unroll 2
  for (int i = 0; i < NN / 8; ++i) {
    int n = i * 8 + wave;
    const float4* wq = (const float4*)(W_q + (size_t)n * NN + lane * 8);
    float4 a0 = wq[0], a1 = wq[1];
    float s = 0.0f;
    s = fmaf(a0.x, qr[0], s); s = fmaf(a0.y, qr[1], s);
    s = fmaf(a0.z, qr[2], s); s = fmaf(a0.w, qr[3], s);
    s = fmaf(a1.x, qr[4], s); s = fmaf(a1.y, qr[5], s);
    s = fmaf(a1.z, qr[6], s); s = fmaf(a1.w, qr[7], s);
    s = waveRedSum(s);
    if (lane == 0) attq[n] = s + b_q[n];
  }
  __syncthreads();

  float aqr[8];
  #pragma unroll
  for (int j = 0; j < 8; ++j) aqr[j] = attq[lane * 8 + j];

  // ---- step 2: scores[k] = b_att + sum_n w_att[n]*tanh(att_q[n]+keys[b,k,n]) ----
  const float batt = b_att[0];
  const float* kbase = keys + (size_t)b * TK * NN;
  #pragma unroll 2
  for (int i = 0; i < TK / 8; ++i) {
    int k = i * 8 + wave;
    const float4* kv = (const float4*)(kbase + (size_t)k * NN + lane * 8);
    float4 k0 = kv[0], k1 = kv[1];
    float kf[8] = {k0.x, k0.y, k0.z, k0.w, k1.x, k1.y, k1.z, k1.w};
    float s = 0.0f;
    #pragma unroll
    for (int j = 0; j < 8; ++j) {
      float t = fast_tanh(aqr[j] + kf[j]);
      s = fmaf(t, wr[j], s);
    }
    s = waveRedSum(s);
    if (lane == 0) sc[k] = s + batt;
  }
  __syncthreads();

  // ---- step 3: softmax over k (512 scores, one per thread) ----
  float my = sc[tid];
  float wm = waveRedMax(my);
  if (lane == 0) red[wave] = wm;
  __syncthreads();
  float bm = red[0];
  #pragma unroll
  for (int w = 1; w < 8; ++w) bm = fmaxf(bm, red[w]);
  float e = EXP2F((my - bm) * 1.4426950408889634f);
  float wsum = waveRedSum(e);
  __syncthreads();                 // all reads of red done before overwrite
  if (lane == 0) red[wave] = wsum;
  __syncthreads();
  float bs = 0.0f;
  #pragma unroll
  for (int w = 0; w < 8; ++w) bs += red[w];
  float p = e * RCPF(bs);
  probs[(size_t)bq * TK + tid] = p;
  sc[tid] = p;                     // own slot only; safe without extra sync
  __syncthreads();

  // ---- step 4: context[n] = sum_k p[k] * values[b,k,n]; thread owns n=tid ----
  const float* vbase = values + (size_t)b * TK * NN + tid;
  float c = 0.0f;
  #pragma unroll 8
  for (int k = 0; k < TK; ++k) {
    c = fmaf(sc[k], vbase[(size_t)k * NN], c);
  }
  cat[NN + tid] = c;
  __syncthreads();

  // ---- step 5: out[o] = tanh(b_out[o] + sum_c cat[c] * W_out[o,c]) ----
  #pragma unroll 2
  for (int i = 0; i < OUTSZ / 8; ++i) {
    int o = i * 8 + wave;
    const float4* wrow = (const float4*)(W_out + (size_t)o * CATSZ + lane * 16);
    float4 a0 = wrow[0], a1 = wrow[1], a2 = wrow[2], a3 = wrow[3];
    float s = 0.0f;
    int base = lane * 16;
    s = fmaf(a0.x, cat[base +  0], s); s = fmaf(a0.y, cat[base +  1], s);
    s = fmaf(a0.z, cat[base +  2], s); s = fmaf(a0.w, cat[base +  3], s);
    s = fmaf(a1.x, cat[base +  4], s); s = fmaf(a1.y, cat[base +  5], s);
    s = fmaf(a1.z, cat[base +  6], s); s = fmaf(a1.w, cat[base +  7], s);
    s = fmaf(a2.x, cat[base +  8], s); s = fmaf(a2.y, cat[base +  9], s);
    s = fmaf(a2.z, cat[base + 10], s); s = fmaf(a2.w, cat[base + 11], s);
    s = fmaf(a3.x, cat[base + 12], s); s = fmaf(a3.y, cat[base + 13], s);
    s = fmaf(a3.z, cat[base + 14], s); s = fmaf(a3.w, cat[base + 15], s);
    s = waveRedSum(s);
    if (lane == 0) {
      float x = s + b_out[o];
      out[(size_t)bq * OUTSZ + o] = fast_tanh(x);
    }
  }
}

extern "C" void kernel_launch(void* const* d_in, const int* in_sizes, int n_in,
                              void* d_out, int out_size, void* d_ws, size_t ws_size,
                              hipStream_t stream) {
  const float* query = (const float*)d_in[0];
  const float* keys  = (const float*)d_in[1];
  const float* vals  = (const float*)d_in[2];
  const float* W_q   = (const float*)d_in[3];
  const float* b_q   = (const float*)d_in[4];
  const float* w_att = (const float*)d_in[5];
  const float* b_att = (const float*)d_in[6];
  const float* W_out = (const float*)d_in[7];
  const float* b_out = (const float*)d_in[8];

  float* out   = (float*)d_out;
  float* probs = out + (size_t)BB * TQ * OUTSZ;   // 262144 floats offset

  attn_fused_kernel<<<dim3(BB * TQ), dim3(512), 0, stream>>>(
      query, keys, vals, W_q, b_q, w_att, b_att, W_out, b_out, out, probs);
}

// Round 4
// 208.141 us; speedup vs baseline: 1.1591x; 1.1591x over previous
//
#include <hip/hip_runtime.h>

// Shape: b=4, t_q=128, t_k=512, n=512, out=512. All fp32.
// Output: [out (4*128*512), probs (4*128*512)].
// Structure: block = (b, pair of q rows), 512 threads, thread t owns
// output index t in every stage; contraction operands stream from global
// (own row) while shared per-n/k data comes from LDS broadcasts.
// NO cross-lane reductions in hot loops (round-2 lesson: VALUBusy 32%,
// stalls on 6-deep dependent shuffle chains).

#define BB    4
#define TQ    128
#define TK    512
#define NN    512
#define OUTSZ 512
#define CATSZ 1024
#define Q     2
#define K2E   2.8853900817779268f   // 2*log2(e)
#define L2E   1.4426950408889634f   // log2(e)

#if __has_builtin(__builtin_amdgcn_exp2f)
#define EXP2F(x) __builtin_amdgcn_exp2f(x)
#else
#define EXP2F(x) exp2f(x)
#endif
#if __has_builtin(__builtin_amdgcn_rcpf)
#define RCPF(x) __builtin_amdgcn_rcpf(x)
#else
#define RCPF(x) (1.0f / (x))
#endif

__device__ __forceinline__ float fast_tanh(float x) {
  float e = EXP2F(x * K2E);
  return fmaf(-2.0f, RCPF(e + 1.0f), 1.0f);
}
__device__ __forceinline__ float waveRedSum(float s) {
  #pragma unroll
  for (int m = 32; m >= 1; m >>= 1) s += __shfl_xor(s, m, 64);
  return s;
}
__device__ __forceinline__ float waveRedMax(float s) {
  #pragma unroll
  for (int m = 32; m >= 1; m >>= 1) s = fmaxf(s, __shfl_xor(s, m, 64));
  return s;
}

// acc += dot(w, v)   (4-wide fma chain)
__device__ __forceinline__ float fma4(float4 w, float4 v, float acc) {
  acc = fmaf(w.x, v.x, acc); acc = fmaf(w.y, v.y, acc);
  acc = fmaf(w.z, v.z, acc); acc = fmaf(w.w, v.w, acc);
  return acc;
}
// score micro-op, 4-wide: acc += w * rcp(exp2(fma(k, K2E, a)) + 1)
__device__ __forceinline__ float sc4(float4 w, float4 k, float4 a, float acc) {
  acc = fmaf(w.x, RCPF(EXP2F(fmaf(k.x, K2E, a.x)) + 1.0f), acc);
  acc = fmaf(w.y, RCPF(EXP2F(fmaf(k.y, K2E, a.y)) + 1.0f), acc);
  acc = fmaf(w.z, RCPF(EXP2F(fmaf(k.z, K2E, a.z)) + 1.0f), acc);
  acc = fmaf(w.w, RCPF(EXP2F(fmaf(k.w, K2E, a.w)) + 1.0f), acc);
  return acc;
}

__global__ __launch_bounds__(512, 4)
void attn_fused(const float* __restrict__ query, const float* __restrict__ keys,
                const float* __restrict__ values, const float* __restrict__ W_q,
                const float* __restrict__ b_q, const float* __restrict__ w_att,
                const float* __restrict__ b_att, const float* __restrict__ W_out,
                const float* __restrict__ b_out,
                float* __restrict__ out, float* __restrict__ probs)
{
  __shared__ __align__(16) float qv[Q][NN];    // query rows
  __shared__ __align__(16) float aqc[Q][NN];   // att_q * 2log2e
  __shared__ __align__(16) float wv[NN];       // w_att
  __shared__ __align__(16) float pr[Q][TK];    // probs
  __shared__ __align__(16) float ctx[Q][NN];   // context
  __shared__ float red[8];

  const int t    = threadIdx.x;
  const int wave = t >> 6, lane = t & 63;
  // XCD-aware swizzle: presumed XCD = blockIdx % 8; give each XCD-pair one
  // batch so keys/values for a batch stay in 2 L2s. (Perf heuristic only.)
  const int p  = blockIdx.x;            // 0..255
  const int b  = (p & 7) >> 1;          // 0..3
  const int qg = ((p >> 3) << 1) | (p & 1);  // 0..63
  const int qabs0 = qg * Q;

  const float batt = b_att[0];

  wv[t] = w_att[t];
  float w_own = w_att[t];
  qv[0][t] = query[((size_t)(b * TQ + qabs0 + 0)) * NN + t];
  qv[1][t] = query[((size_t)(b * TQ + qabs0 + 1)) * NN + t];
  __syncthreads();

  // sumW = sum_n w_att[n]  (one-time reduction; cold path)
  float wpart = waveRedSum(w_own);
  if (lane == 0) red[wave] = wpart;
  __syncthreads();
  const float sumW = red[0]+red[1]+red[2]+red[3]+red[4]+red[5]+red[6]+red[7];
  // red reused in softmax; ordered by the sync after step 1.

  // ---- step 1: thread t owns n=t: aqc[q][t] = (b_q[t] + sum_d qv[q][d]*W_q[t,d]) * K2E
  {
    const float4* wq4 = (const float4*)(W_q + (size_t)t * NN);
    const float4* x4  = (const float4*)qv[0];
    const float4* y4  = (const float4*)qv[1];
    float a0a=0,a0b=0,a1a=0,a1b=0;
    #pragma unroll 2
    for (int c = 0; c < NN/16; ++c) {
      float4 wA = wq4[4*c+0], wB = wq4[4*c+1], wC = wq4[4*c+2], wD = wq4[4*c+3];
      float4 xA = x4[4*c+0], xB = x4[4*c+1], xC = x4[4*c+2], xD = x4[4*c+3];
      a0a = fma4(wA, xA, a0a); a0b = fma4(wB, xB, a0b);
      a0a = fma4(wC, xC, a0a); a0b = fma4(wD, xD, a0b);
      float4 yA = y4[4*c+0], yB = y4[4*c+1], yC = y4[4*c+2], yD = y4[4*c+3];
      a1a = fma4(wA, yA, a1a); a1b = fma4(wB, yB, a1b);
      a1a = fma4(wC, yC, a1a); a1b = fma4(wD, yD, a1b);
    }
    float bq = b_q[t];
    aqc[0][t] = (a0a + a0b + bq) * K2E;
    aqc[1][t] = (a1a + a1b + bq) * K2E;
  }
  __syncthreads();

  // ---- step 2 (hot): thread t owns k=t:
  //   score[q] = batt + sumW - 2 * sum_n wv[n] * rcp(exp2(keys[k][n]*K2E + aqc[q][n]) + 1)
  float sc2[Q];
  {
    const float4* kr4 = (const float4*)(keys + ((size_t)b * TK + t) * NN);
    const float4* a40 = (const float4*)aqc[0];
    const float4* a41 = (const float4*)aqc[1];
    const float4* w4  = (const float4*)wv;
    float s0 = 0.f, s1 = 0.f;
    #pragma unroll 2
    for (int c = 0; c < NN/16; ++c) {
      float4 kA = kr4[4*c+0], kB = kr4[4*c+1], kC = kr4[4*c+2], kD = kr4[4*c+3];
      float4 wA = w4[4*c+0],  wB = w4[4*c+1],  wC = w4[4*c+2],  wD = w4[4*c+3];
      float4 aA = a40[4*c+0], aB = a40[4*c+1], aC = a40[4*c+2], aD = a40[4*c+3];
      s0 = sc4(wA, kA, aA, s0); s0 = sc4(wB, kB, aB, s0);
      s0 = sc4(wC, kC, aC, s0); s0 = sc4(wD, kD, aD, s0);
      float4 bA = a41[4*c+0], bB = a41[4*c+1], bC = a41[4*c+2], bD = a41[4*c+3];
      s1 = sc4(wA, kA, bA, s1); s1 = sc4(wB, kB, bB, s1);
      s1 = sc4(wC, kC, bC, s1); s1 = sc4(wD, kD, bD, s1);
    }
    sc2[0] = batt + sumW - 2.0f * s0;
    sc2[1] = batt + sumW - 2.0f * s1;
  }

  // ---- softmax (cold; one reduction pair per q per block)
  #pragma unroll
  for (int q = 0; q < Q; ++q) {
    __syncthreads();                       // protect red reuse
    float m = waveRedMax(sc2[q]);
    if (lane == 0) red[wave] = m;
    __syncthreads();
    float bm = fmaxf(fmaxf(fmaxf(red[0],red[1]),fmaxf(red[2],red[3])),
                     fmaxf(fmaxf(red[4],red[5]),fmaxf(red[6],red[7])));
    float e = EXP2F((sc2[q] - bm) * L2E);
    float se = waveRedSum(e);
    __syncthreads();
    if (lane == 0) red[wave] = se;
    __syncthreads();
    float bs = red[0]+red[1]+red[2]+red[3]+red[4]+red[5]+red[6]+red[7];
    float pv = e * RCPF(bs);
    pr[q][t] = pv;
    probs[((size_t)(b * TQ + qabs0 + q)) * TK + t] = pv;
  }
  __syncthreads();

  // ---- step 4: thread t owns n=t: ctx[q][t] = sum_k pr[q][k] * values[b,k,t]
  {
    const float* vcol = values + (size_t)b * TK * NN + t;   // coalesced
    const float4* p40 = (const float4*)pr[0];
    const float4* p41 = (const float4*)pr[1];
    float c0a=0,c0b=0,c1a=0,c1b=0;
    #pragma unroll 2
    for (int k = 0; k < TK; k += 8) {
      float v0 = vcol[(size_t)(k+0)*NN]; float v1 = vcol[(size_t)(k+1)*NN];
      float v2 = vcol[(size_t)(k+2)*NN]; float v3 = vcol[(size_t)(k+3)*NN];
      float v4 = vcol[(size_t)(k+4)*NN]; float v5 = vcol[(size_t)(k+5)*NN];
      float v6 = vcol[(size_t)(k+6)*NN]; float v7 = vcol[(size_t)(k+7)*NN];
      float4 pA = p40[k>>2], pB = p40[(k>>2)+1];
      float4 qA = p41[k>>2], qB = p41[(k>>2)+1];
      c0a = fmaf(pA.x,v0,c0a); c0a = fmaf(pA.y,v1,c0a);
      c0b = fmaf(pA.z,v2,c0b); c0b = fmaf(pA.w,v3,c0b);
      c0a = fmaf(pB.x,v4,c0a); c0a = fmaf(pB.y,v5,c0a);
      c0b = fmaf(pB.z,v6,c0b); c0b = fmaf(pB.w,v7,c0b);
      c1a = fmaf(qA.x,v0,c1a); c1a = fmaf(qA.y,v1,c1a);
      c1b = fmaf(qA.z,v2,c1b); c1b = fmaf(qA.w,v3,c1b);
      c1a = fmaf(qB.x,v4,c1a); c1a = fmaf(qB.y,v5,c1a);
      c1b = fmaf(qB.z,v6,c1b); c1b = fmaf(qB.w,v7,c1b);
    }
    ctx[0][t] = c0a + c0b;
    ctx[1][t] = c1a + c1b;
  }
  __syncthreads();

  // ---- step 5: thread t owns o=t: out[q][t] = tanh(b_out[t] + W_out[t,:] . cat[q])
  {
    const float4* wo4 = (const float4*)(W_out + (size_t)t * CATSZ);
    const float4* x4  = (const float4*)qv[0];
    const float4* y4  = (const float4*)qv[1];
    float o0a=0,o0b=0,o1a=0,o1b=0;
    #pragma unroll 2
    for (int c = 0; c < NN/16; ++c) {
      float4 wA = wo4[4*c+0], wB = wo4[4*c+1], wC = wo4[4*c+2], wD = wo4[4*c+3];
      float4 xA = x4[4*c+0], xB = x4[4*c+1], xC = x4[4*c+2], xD = x4[4*c+3];
      o0a = fma4(wA, xA, o0a); o0b = fma4(wB, xB, o0b);
      o0a = fma4(wC, xC, o0a); o0b = fma4(wD, xD, o0b);
      float4 yA = y4[4*c+0], yB = y4[4*c+1], yC = y4[4*c+2], yD = y4[4*c+3];
      o1a = fma4(wA, yA, o1a); o1b = fma4(wB, yB, o1b);
      o1a = fma4(wC, yC, o1a); o1b = fma4(wD, yD, o1b);
    }
    const float4* wo4b = wo4 + NN/4;
    const float4* u4 = (const float4*)ctx[0];
    const float4* v4 = (const float4*)ctx[1];
    #pragma unroll 2
    for (int c = 0; c < NN/16; ++c) {
      float4 wA = wo4b[4*c+0], wB = wo4b[4*c+1], wC = wo4b[4*c+2], wD = wo4b[4*c+3];
      float4 xA = u4[4*c+0], xB = u4[4*c+1], xC = u4[4*c+2], xD = u4[4*c+3];
      o0a = fma4(wA, xA, o0a); o0b = fma4(wB, xB, o0b);
      o0a = fma4(wC, xC, o0a); o0b = fma4(wD, xD, o0b);
      float4 yA = v4[4*c+0], yB = v4[4*c+1], yC = v4[4*c+2], yD = v4[4*c+3];
      o1a = fma4(wA, yA, o1a); o1b = fma4(wB, yB, o1b);
      o1a = fma4(wC, yC, o1a); o1b = fma4(wD, yD, o1b);
    }
    float bo = b_out[t];
    out[((size_t)(b * TQ + qabs0 + 0)) * OUTSZ + t] = fast_tanh(o0a + o0b + bo);
    out[((size_t)(b * TQ + qabs0 + 1)) * OUTSZ + t] = fast_tanh(o1a + o1b + bo);
  }
}

extern "C" void kernel_launch(void* const* d_in, const int* in_sizes, int n_in,
                              void* d_out, int out_size, void* d_ws, size_t ws_size,
                              hipStream_t stream) {
  const float* query = (const float*)d_in[0];
  const float* keys  = (const float*)d_in[1];
  const float* vals  = (const float*)d_in[2];
  const float* W_q   = (const float*)d_in[3];
  const float* b_q   = (const float*)d_in[4];
  const float* w_att = (const float*)d_in[5];
  const float* b_att = (const float*)d_in[6];
  const float* W_out = (const float*)d_in[7];
  const float* b_out = (const float*)d_in[8];

  float* out   = (float*)d_out;
  float* probs = out + (size_t)BB * TQ * OUTSZ;

  attn_fused<<<dim3(BB * TQ / Q), dim3(512), 0, stream>>>(
      query, keys, vals, W_q, b_q, w_att, b_att, W_out, b_out, out, probs);
}